// Round 1
// baseline (2080.826 us; speedup 1.0000x reference)
//
#include <hip/hip_runtime.h>

#define NFEAT 512
#define NHID  256

// ---------------- GEMM: C[M x 256] = A[M x K] @ B[K x 256], fp32 ----------------
// 64x64 tile, 256 threads, 4x4 microtile per thread.
__global__ __launch_bounds__(256) void gemm_tile(
    const float* __restrict__ A, const float* __restrict__ B,
    float* __restrict__ C, int M, int K)
{
    const int BM = 64, BN = 64, BK = 16;
    __shared__ float As[BK][BM];   // A tile stored transposed: As[k][m]
    __shared__ float Bs[BK][BN];

    int tid  = threadIdx.x;
    int by   = blockIdx.x;           // row tile
    int bx   = blockIdx.y;           // col tile (0..3)
    int row0 = by * BM;
    int col0 = bx * BN;

    // A-load: r = tid/4 (0..63), float4 along K at (tid%4)*4
    int ar = tid >> 2;
    int ac = (tid & 3) * 4;
    // B-load: r = tid/16 (0..15), float4 along N at (tid%16)*4
    int br = tid >> 4;
    int bc = (tid & 15) * 4;

    int tx = tid & 15;   // output col group
    int ty = tid >> 4;   // output row group

    float acc[4][4] = {};

    for (int k0 = 0; k0 < K; k0 += BK) {
        float4 av = make_float4(0.f, 0.f, 0.f, 0.f);
        int gr = row0 + ar;
        if (gr < M) av = *(const float4*)(A + (size_t)gr * K + k0 + ac);
        As[ac + 0][ar] = av.x;
        As[ac + 1][ar] = av.y;
        As[ac + 2][ar] = av.z;
        As[ac + 3][ar] = av.w;
        float4 bv = *(const float4*)(B + (size_t)(k0 + br) * NHID + col0 + bc);
        *(float4*)(&Bs[br][bc]) = bv;
        __syncthreads();
        #pragma unroll
        for (int kk = 0; kk < BK; ++kk) {
            float4 a4 = *(const float4*)(&As[kk][ty * 4]);
            float4 b4 = *(const float4*)(&Bs[kk][tx * 4]);
            float ae[4] = {a4.x, a4.y, a4.z, a4.w};
            float be[4] = {b4.x, b4.y, b4.z, b4.w};
            #pragma unroll
            for (int i = 0; i < 4; ++i)
                #pragma unroll
                for (int j = 0; j < 4; ++j)
                    acc[i][j] += ae[i] * be[j];
        }
        __syncthreads();
    }

    #pragma unroll
    for (int i = 0; i < 4; ++i) {
        int gr = row0 + ty * 4 + i;
        if (gr < M) {
            float4 o = make_float4(acc[i][0], acc[i][1], acc[i][2], acc[i][3]);
            *(float4*)(C + (size_t)gr * NHID + col0 + tx * 4) = o;
        }
    }
}

// ---------------- CSR build ----------------
__global__ void hist_kernel(const int* __restrict__ rows, int* __restrict__ counts, int E)
{
    int i = blockIdx.x * blockDim.x + threadIdx.x;
    if (i < E) atomicAdd(&counts[rows[i]], 1);
}

// Single-block scan: row_ptr[0]=0, row_ptr[i+1]=cumsum(counts[0..i])
__global__ __launch_bounds__(1024) void scan_kernel(
    const int* __restrict__ counts, int* __restrict__ row_ptr, int n)
{
    __shared__ int wsum[16];
    __shared__ int woff[17];
    __shared__ int carry_s;
    int tid  = threadIdx.x;
    int lane = tid & 63;
    int wid  = tid >> 6;
    if (tid == 0) { carry_s = 0; row_ptr[0] = 0; }
    __syncthreads();
    for (int base = 0; base < n; base += 1024) {
        int i = base + tid;
        int v = (i < n) ? counts[i] : 0;
        int x = v;
        #pragma unroll
        for (int off = 1; off < 64; off <<= 1) {
            int y = __shfl_up(x, off);
            if (lane >= off) x += y;
        }
        if (lane == 63) wsum[wid] = x;
        __syncthreads();
        if (tid == 0) {
            int s = 0;
            #pragma unroll
            for (int w = 0; w < 16; ++w) { woff[w] = s; s += wsum[w]; }
            woff[16] = s;
        }
        __syncthreads();
        int c = carry_s;
        if (i < n) row_ptr[i + 1] = x + woff[wid] + c;
        __syncthreads();
        if (tid == 0) carry_s = c + woff[16];
        __syncthreads();
    }
}

__global__ void scatter_kernel(
    const int* __restrict__ erow, const int* __restrict__ ecol,
    const float* __restrict__ eval, const int* __restrict__ row_ptr,
    int* __restrict__ fill, int* __restrict__ cols_s, float* __restrict__ vals_s, int E)
{
    int i = blockIdx.x * blockDim.x + threadIdx.x;
    if (i < E) {
        int r = erow[i];
        int p = row_ptr[r] + atomicAdd(&fill[r], 1);
        cols_s[p] = ecol[i];
        vals_s[p] = eval[i];
    }
}

// ---------------- SpMM (CSR, wave-per-row) + bias + PReLU ----------------
__global__ __launch_bounds__(256) void spmm_kernel(
    const int* __restrict__ row_ptr, const int* __restrict__ cols,
    const float* __restrict__ vals, const float* __restrict__ dense,
    const float* __restrict__ bias, const float* __restrict__ alpha_p,
    float* __restrict__ out, int nrows)
{
    int wid  = (blockIdx.x * blockDim.x + threadIdx.x) >> 6;
    int lane = threadIdx.x & 63;
    if (wid >= nrows) return;
    int s = row_ptr[wid];
    int e = row_ptr[wid + 1];
    int fo = lane * 4;

    float ax = 0.f, ay = 0.f, az = 0.f, aw = 0.f;
    int i = s;
    for (; i + 1 < e; i += 2) {
        int   c0 = cols[i],  c1 = cols[i + 1];
        float v0 = vals[i],  v1 = vals[i + 1];
        float4 t0 = *(const float4*)(dense + (size_t)c0 * NHID + fo);
        float4 t1 = *(const float4*)(dense + (size_t)c1 * NHID + fo);
        ax += v0 * t0.x; ay += v0 * t0.y; az += v0 * t0.z; aw += v0 * t0.w;
        ax += v1 * t1.x; ay += v1 * t1.y; az += v1 * t1.z; aw += v1 * t1.w;
    }
    if (i < e) {
        int   c0 = cols[i];
        float v0 = vals[i];
        float4 t0 = *(const float4*)(dense + (size_t)c0 * NHID + fo);
        ax += v0 * t0.x; ay += v0 * t0.y; az += v0 * t0.z; aw += v0 * t0.w;
    }

    float alpha = alpha_p[0];
    float4 b = *(const float4*)(bias + fo);
    float r0 = ax + b.x; r0 = (r0 >= 0.f) ? r0 : alpha * r0;
    float r1 = ay + b.y; r1 = (r1 >= 0.f) ? r1 : alpha * r1;
    float r2 = az + b.z; r2 = (r2 >= 0.f) ? r2 : alpha * r2;
    float r3 = aw + b.w; r3 = (r3 >= 0.f) ? r3 : alpha * r3;
    *(float4*)(out + (size_t)wid * NHID + fo) = make_float4(r0, r1, r2, r3);
}

extern "C" void kernel_launch(void* const* d_in, const int* in_sizes, int n_in,
                              void* d_out, int out_size, void* d_ws, size_t ws_size,
                              hipStream_t stream)
{
    const float* x     = (const float*)d_in[0];
    const int*   erow  = (const int*)d_in[1];
    const int*   ecol  = (const int*)d_in[2];
    const float* eval  = (const float*)d_in[3];
    const float* W1    = (const float*)d_in[4];
    const float* b1    = (const float*)d_in[5];
    const float* W2    = (const float*)d_in[6];
    const float* b2    = (const float*)d_in[7];
    const float* alpha = (const float*)d_in[8];

    int N = in_sizes[0] / NFEAT;   // 100000
    int E = in_sizes[1];           // 3200000
    float* out = (float*)d_out;

    // Workspace layout (~128.8 MB)
    char* wsp = (char*)d_ws;
    float* support = (float*)wsp;  wsp += (size_t)N * NHID * sizeof(float);
    int*   cols_s  = (int*)wsp;    wsp += (size_t)E * sizeof(int);
    float* vals_s  = (float*)wsp;  wsp += (size_t)E * sizeof(float);
    int*   row_ptr = (int*)wsp;    wsp += (size_t)(N + 1) * sizeof(int);
    int*   fill    = (int*)wsp;    wsp += (size_t)N * sizeof(int);

    // ---- CSR build (reused by both layers) ----
    hipMemsetAsync(fill, 0, (size_t)N * sizeof(int), stream);
    hist_kernel<<<(E + 255) / 256, 256, 0, stream>>>(erow, fill, E);
    scan_kernel<<<1, 1024, 0, stream>>>(fill, row_ptr, N);
    hipMemsetAsync(fill, 0, (size_t)N * sizeof(int), stream);
    scatter_kernel<<<(E + 255) / 256, 256, 0, stream>>>(erow, ecol, eval, row_ptr, fill,
                                                        cols_s, vals_s, E);

    dim3 ggrid((N + 63) / 64, NHID / 64);
    int  spmm_blocks = (N * 64 + 255) / 256;   // one wave per row

    // ---- Layer 1: support = x@W1 ; out(h1) = prelu(spmm(support)+b1) ----
    gemm_tile<<<ggrid, 256, 0, stream>>>(x, W1, support, N, NFEAT);
    spmm_kernel<<<spmm_blocks, 256, 0, stream>>>(row_ptr, cols_s, vals_s, support, b1, alpha, out, N);

    // ---- Layer 2: support = h1@W2 ; out = prelu(spmm(support)+b2) ----
    gemm_tile<<<ggrid, 256, 0, stream>>>(out, W2, support, N, NHID);
    spmm_kernel<<<spmm_blocks, 256, 0, stream>>>(row_ptr, cols_s, vals_s, support, b2, alpha, out, N);
}

// Round 2
// 1344.149 us; speedup vs baseline: 1.5481x; 1.5481x over previous
//
#include <hip/hip_runtime.h>

#define NHID 256

typedef __attribute__((ext_vector_type(8))) short short8;
typedef __attribute__((ext_vector_type(4))) float floatx4;

static __device__ __forceinline__ short f2bf(float f) {
    unsigned u = __float_as_uint(f);
    unsigned r = (u + 0x7fffu + ((u >> 16) & 1u)) >> 16;
    return (short)r;
}
static __device__ __forceinline__ float bf2f(short s) {
    return __uint_as_float(((unsigned)(unsigned short)s) << 16);
}

// ---------------- W transpose+cast: Wt[n][k] bf16 from W[k][n] fp32 ----------------
__global__ void transpose_cast(const float* __restrict__ W, short* __restrict__ Wt, int K)
{
    int idx = blockIdx.x * 256 + threadIdx.x;
    if (idx >= K * NHID) return;
    int k = idx >> 8;          // row in W
    int n = idx & 255;         // col in W
    Wt[(size_t)n * K + k] = f2bf(W[idx]);
}

// ---------------- MFMA GEMM: C[M x 256](bf16) = A[M x K] @ Bt[n][k](bf16) ----------
// 128x128 block tile, BK=32, 4 waves (2x2), each wave 64x64 = 4x4 MFMA 16x16x32 tiles.
template<bool ABF16>
__global__ __launch_bounds__(256) void gemm_mfma(
    const void* __restrict__ Ap, const short* __restrict__ Bt,
    short* __restrict__ C, int M, int K)
{
    __shared__ __align__(16) short As[128][40];   // [m][k], pad 32->40 vs bank conflicts
    __shared__ __align__(16) short Bs[128][40];   // [n][k]

    int tid  = threadIdx.x;
    int m0   = blockIdx.y * 128;
    int n0   = blockIdx.x * 128;
    int lane = tid & 63;
    int wid  = tid >> 6;
    int wm   = wid >> 1;          // 0..1
    int wn   = wid & 1;           // 0..1
    int quad = lane >> 4;         // 0..3
    int l16  = lane & 15;

    floatx4 acc[4][4] = {};

    for (int k0 = 0; k0 < K; k0 += 32) {
        if (ABF16) {
            const short* A = (const short*)Ap;
            int tr = tid >> 2, tc = (tid & 3) * 8;
            #pragma unroll
            for (int p = 0; p < 2; ++p) {
                int m = p * 64 + tr, gm = m0 + m;
                int4 v = make_int4(0, 0, 0, 0);
                if (gm < M) v = *(const int4*)(A + (size_t)gm * K + k0 + tc);
                *(int4*)&As[m][tc] = v;
            }
        } else {
            const float* A = (const float*)Ap;
            int tr = tid >> 3, tc = (tid & 7) * 4;
            #pragma unroll
            for (int p = 0; p < 4; ++p) {
                int m = p * 32 + tr, gm = m0 + m;
                float4 v = make_float4(0.f, 0.f, 0.f, 0.f);
                if (gm < M) v = *(const float4*)(A + (size_t)gm * K + k0 + tc);
                short4 s;
                s.x = f2bf(v.x); s.y = f2bf(v.y); s.z = f2bf(v.z); s.w = f2bf(v.w);
                *(short4*)&As[m][tc] = s;
            }
        }
        {
            int nr = tid >> 2, nc = (tid & 3) * 8;
            #pragma unroll
            for (int p = 0; p < 2; ++p) {
                int n = p * 64 + nr;
                *(int4*)&Bs[n][nc] = *(const int4*)(Bt + (size_t)(n0 + n) * K + k0 + nc);
            }
        }
        __syncthreads();

        short8 af[4], bfr[4];
        #pragma unroll
        for (int t = 0; t < 4; ++t) {
            af[t]  = *(const short8*)&As[wm * 64 + t * 16 + l16][quad * 8];
            bfr[t] = *(const short8*)&Bs[wn * 64 + t * 16 + l16][quad * 8];
        }
        #pragma unroll
        for (int tm = 0; tm < 4; ++tm)
            #pragma unroll
            for (int tn = 0; tn < 4; ++tn)
                acc[tm][tn] = __builtin_amdgcn_mfma_f32_16x16x32_bf16(
                    af[tm], bfr[tn], acc[tm][tn], 0, 0, 0);
        __syncthreads();
    }

    // C/D layout: col = lane&15, row = quad*4 + reg
    #pragma unroll
    for (int tm = 0; tm < 4; ++tm) {
        #pragma unroll
        for (int r = 0; r < 4; ++r) {
            int row = m0 + wm * 64 + tm * 16 + quad * 4 + r;
            if (row < M) {
                #pragma unroll
                for (int tn = 0; tn < 4; ++tn) {
                    int col = n0 + wn * 64 + tn * 16 + l16;
                    C[(size_t)row * NHID + col] = f2bf(acc[tm][tn][r]);
                }
            }
        }
    }
}

// ---------------- CSR build ----------------
__global__ void hist_kernel(const int* __restrict__ rows, int* __restrict__ counts, int E)
{
    int i = blockIdx.x * blockDim.x + threadIdx.x;
    if (i < E) atomicAdd(&counts[rows[i]], 1);
}

__global__ __launch_bounds__(1024) void scan_kernel(
    const int* __restrict__ counts, int* __restrict__ row_ptr, int n)
{
    __shared__ int wsum[16];
    __shared__ int woff[17];
    __shared__ int carry_s;
    int tid  = threadIdx.x;
    int lane = tid & 63;
    int wid  = tid >> 6;
    if (tid == 0) { carry_s = 0; row_ptr[0] = 0; }
    __syncthreads();
    for (int base = 0; base < n; base += 1024) {
        int i = base + tid;
        int v = (i < n) ? counts[i] : 0;
        int x = v;
        #pragma unroll
        for (int off = 1; off < 64; off <<= 1) {
            int y = __shfl_up(x, off);
            if (lane >= off) x += y;
        }
        if (lane == 63) wsum[wid] = x;
        __syncthreads();
        if (tid == 0) {
            int s = 0;
            #pragma unroll
            for (int w = 0; w < 16; ++w) { woff[w] = s; s += wsum[w]; }
            woff[16] = s;
        }
        __syncthreads();
        int c = carry_s;
        if (i < n) row_ptr[i + 1] = x + woff[wid] + c;
        __syncthreads();
        if (tid == 0) carry_s = c + woff[16];
        __syncthreads();
    }
}

__global__ void scatter_kernel(
    const int* __restrict__ erow, const int* __restrict__ ecol,
    const float* __restrict__ eval, const int* __restrict__ row_ptr,
    int* __restrict__ fill, int* __restrict__ cols_s, float* __restrict__ vals_s, int E)
{
    int i = blockIdx.x * blockDim.x + threadIdx.x;
    if (i < E) {
        int r = erow[i];
        int p = row_ptr[r] + atomicAdd(&fill[r], 1);
        cols_s[p] = ecol[i];
        vals_s[p] = eval[i];
    }
}

// ---------------- SpMM (CSR, wave-per-row, bf16 dense) + bias + PReLU -------------
template<bool OUT_BF16>
__global__ __launch_bounds__(256) void spmm_bf16(
    const int* __restrict__ row_ptr, const int* __restrict__ cols,
    const float* __restrict__ vals, const short* __restrict__ dense,
    const float* __restrict__ bias, const float* __restrict__ alpha_p,
    void* __restrict__ outp, int nrows)
{
    int wid  = (blockIdx.x * blockDim.x + threadIdx.x) >> 6;
    int lane = threadIdx.x & 63;
    if (wid >= nrows) return;
    int s = row_ptr[wid];
    int e = row_ptr[wid + 1];
    int fo = lane * 4;

    float a0 = 0.f, a1 = 0.f, a2 = 0.f, a3 = 0.f;
    int i = s;
    for (; i + 1 < e; i += 2) {
        int   c0 = cols[i],  c1 = cols[i + 1];
        float v0 = vals[i],  v1 = vals[i + 1];
        short4 t0 = *(const short4*)(dense + (size_t)c0 * NHID + fo);
        short4 t1 = *(const short4*)(dense + (size_t)c1 * NHID + fo);
        a0 += v0 * bf2f(t0.x); a1 += v0 * bf2f(t0.y);
        a2 += v0 * bf2f(t0.z); a3 += v0 * bf2f(t0.w);
        a0 += v1 * bf2f(t1.x); a1 += v1 * bf2f(t1.y);
        a2 += v1 * bf2f(t1.z); a3 += v1 * bf2f(t1.w);
    }
    if (i < e) {
        int   c0 = cols[i];
        float v0 = vals[i];
        short4 t0 = *(const short4*)(dense + (size_t)c0 * NHID + fo);
        a0 += v0 * bf2f(t0.x); a1 += v0 * bf2f(t0.y);
        a2 += v0 * bf2f(t0.z); a3 += v0 * bf2f(t0.w);
    }

    float alpha = alpha_p[0];
    float4 b = *(const float4*)(bias + fo);
    float r0 = a0 + b.x; r0 = (r0 >= 0.f) ? r0 : alpha * r0;
    float r1 = a1 + b.y; r1 = (r1 >= 0.f) ? r1 : alpha * r1;
    float r2 = a2 + b.z; r2 = (r2 >= 0.f) ? r2 : alpha * r2;
    float r3 = a3 + b.w; r3 = (r3 >= 0.f) ? r3 : alpha * r3;

    if (OUT_BF16) {
        short4 o;
        o.x = f2bf(r0); o.y = f2bf(r1); o.z = f2bf(r2); o.w = f2bf(r3);
        *(short4*)((short*)outp + (size_t)wid * NHID + fo) = o;
    } else {
        *(float4*)((float*)outp + (size_t)wid * NHID + fo) = make_float4(r0, r1, r2, r3);
    }
}

extern "C" void kernel_launch(void* const* d_in, const int* in_sizes, int n_in,
                              void* d_out, int out_size, void* d_ws, size_t ws_size,
                              hipStream_t stream)
{
    const float* x     = (const float*)d_in[0];
    const int*   erow  = (const int*)d_in[1];
    const int*   ecol  = (const int*)d_in[2];
    const float* eval  = (const float*)d_in[3];
    const float* W1    = (const float*)d_in[4];
    const float* b1    = (const float*)d_in[5];
    const float* W2    = (const float*)d_in[6];
    const float* b2    = (const float*)d_in[7];
    const float* alpha = (const float*)d_in[8];

    int NFEAT = 512;
    int N = in_sizes[0] / NFEAT;   // 100000
    int E = in_sizes[1];           // 3200000
    float* out = (float*)d_out;

    // Workspace layout (~128.79 MB, fits round-1 footprint)
    char* wsp = (char*)d_ws;
    short* support_b = (short*)wsp;  wsp += (size_t)N * NHID * sizeof(short);  // 51.2 MB
    short* h1b       = (short*)wsp;  wsp += (size_t)N * NHID * sizeof(short);  // 51.2 MB
    int*   cols_s    = (int*)wsp;    wsp += (size_t)E * sizeof(int);           // 12.8 MB
    float* vals_s    = (float*)wsp;  wsp += (size_t)E * sizeof(float);         // 12.8 MB
    int*   row_ptr   = (int*)wsp;    wsp += ((size_t)(N + 1) * sizeof(int) + 15) & ~(size_t)15;
    short* W1t       = (short*)wsp;  wsp += (size_t)NFEAT * NHID * sizeof(short);
    short* W2t       = (short*)wsp;  wsp += (size_t)NHID * NHID * sizeof(short);
    int*   fill      = (int*)h1b;    // alias: h1b not live during CSR build

    // ---- Weight transpose+cast (tiny) ----
    transpose_cast<<<(NFEAT * NHID + 255) / 256, 256, 0, stream>>>(W1, W1t, NFEAT);
    transpose_cast<<<(NHID * NHID + 255) / 256, 256, 0, stream>>>(W2, W2t, NHID);

    // ---- CSR build (reused by both layers) ----
    hipMemsetAsync(fill, 0, (size_t)N * sizeof(int), stream);
    hist_kernel<<<(E + 255) / 256, 256, 0, stream>>>(erow, fill, E);
    scan_kernel<<<1, 1024, 0, stream>>>(fill, row_ptr, N);
    hipMemsetAsync(fill, 0, (size_t)N * sizeof(int), stream);
    scatter_kernel<<<(E + 255) / 256, 256, 0, stream>>>(erow, ecol, eval, row_ptr, fill,
                                                        cols_s, vals_s, E);

    dim3 ggrid(2, (N + 127) / 128);          // x = n-tile (2), y = m-tile
    int  spmm_blocks = (N + 3) / 4;          // 4 waves/block, wave per row

    // ---- Layer 1 ----
    gemm_mfma<false><<<ggrid, 256, 0, stream>>>(x, W1t, support_b, N, NFEAT);
    spmm_bf16<true><<<spmm_blocks, 256, 0, stream>>>(row_ptr, cols_s, vals_s, support_b,
                                                     b1, alpha, h1b, N);
    // ---- Layer 2 ----
    gemm_mfma<true><<<ggrid, 256, 0, stream>>>(h1b, W2t, support_b, N, NHID);
    spmm_bf16<false><<<spmm_blocks, 256, 0, stream>>>(row_ptr, cols_s, vals_s, support_b,
                                                      b2, alpha, out, N);
}

// Round 3
// 1174.296 us; speedup vs baseline: 1.7720x; 1.1446x over previous
//
#include <hip/hip_runtime.h>

#define NHID 256

typedef __attribute__((ext_vector_type(8))) short short8;
typedef __attribute__((ext_vector_type(4))) float floatx4;

static __device__ __forceinline__ short f2bf(float f) {
    unsigned u = __float_as_uint(f);
    unsigned r = (u + 0x7fffu + ((u >> 16) & 1u)) >> 16;
    return (short)r;
}
static __device__ __forceinline__ unsigned pk2(float a, float b) {
    return ((unsigned)(unsigned short)f2bf(a)) | (((unsigned)(unsigned short)f2bf(b)) << 16);
}

// ---------------- W transpose+cast: Wt[n][k] bf16 from W[k][n] fp32 ----------------
__global__ void transpose_cast(const float* __restrict__ W, short* __restrict__ Wt, int K)
{
    int idx = blockIdx.x * 256 + threadIdx.x;
    if (idx >= K * NHID) return;
    int k = idx >> 8;
    int n = idx & 255;
    Wt[(size_t)n * K + k] = f2bf(W[idx]);
}

// ---------------- MFMA GEMM: C[M x 256](bf16) = A[M x K] @ Bt[n][k](bf16) ----------
template<bool ABF16>
__global__ __launch_bounds__(256) void gemm_mfma(
    const void* __restrict__ Ap, const short* __restrict__ Bt,
    short* __restrict__ C, int M, int K)
{
    __shared__ __align__(16) short As[128][40];
    __shared__ __align__(16) short Bs[128][40];

    int tid  = threadIdx.x;
    int m0   = blockIdx.y * 128;
    int n0   = blockIdx.x * 128;
    int lane = tid & 63;
    int wid  = tid >> 6;
    int wm   = wid >> 1;
    int wn   = wid & 1;
    int quad = lane >> 4;
    int l16  = lane & 15;

    floatx4 acc[4][4] = {};

    for (int k0 = 0; k0 < K; k0 += 32) {
        if (ABF16) {
            const short* A = (const short*)Ap;
            int tr = tid >> 2, tc = (tid & 3) * 8;
            #pragma unroll
            for (int p = 0; p < 2; ++p) {
                int m = p * 64 + tr, gm = m0 + m;
                int4 v = make_int4(0, 0, 0, 0);
                if (gm < M) v = *(const int4*)(A + (size_t)gm * K + k0 + tc);
                *(int4*)&As[m][tc] = v;
            }
        } else {
            const float* A = (const float*)Ap;
            int tr = tid >> 3, tc = (tid & 7) * 4;
            #pragma unroll
            for (int p = 0; p < 4; ++p) {
                int m = p * 32 + tr, gm = m0 + m;
                float4 v = make_float4(0.f, 0.f, 0.f, 0.f);
                if (gm < M) v = *(const float4*)(A + (size_t)gm * K + k0 + tc);
                short4 s;
                s.x = f2bf(v.x); s.y = f2bf(v.y); s.z = f2bf(v.z); s.w = f2bf(v.w);
                *(short4*)&As[m][tc] = s;
            }
        }
        {
            int nr = tid >> 2, nc = (tid & 3) * 8;
            #pragma unroll
            for (int p = 0; p < 2; ++p) {
                int n = p * 64 + nr;
                *(int4*)&Bs[n][nc] = *(const int4*)(Bt + (size_t)(n0 + n) * K + k0 + nc);
            }
        }
        __syncthreads();

        short8 af[4], bfr[4];
        #pragma unroll
        for (int t = 0; t < 4; ++t) {
            af[t]  = *(const short8*)&As[wm * 64 + t * 16 + l16][quad * 8];
            bfr[t] = *(const short8*)&Bs[wn * 64 + t * 16 + l16][quad * 8];
        }
        #pragma unroll
        for (int tm = 0; tm < 4; ++tm)
            #pragma unroll
            for (int tn = 0; tn < 4; ++tn)
                acc[tm][tn] = __builtin_amdgcn_mfma_f32_16x16x32_bf16(
                    af[tm], bfr[tn], acc[tm][tn], 0, 0, 0);
        __syncthreads();
    }

    #pragma unroll
    for (int tm = 0; tm < 4; ++tm) {
        #pragma unroll
        for (int r = 0; r < 4; ++r) {
            int row = m0 + wm * 64 + tm * 16 + quad * 4 + r;
            if (row < M) {
                #pragma unroll
                for (int tn = 0; tn < 4; ++tn) {
                    int col = n0 + wn * 64 + tn * 16 + l16;
                    C[(size_t)row * NHID + col] = f2bf(acc[tm][tn][r]);
                }
            }
        }
    }
}

// ---------------- CSR build ----------------
__global__ void hist_kernel(const int* __restrict__ rows, int* __restrict__ counts, int E)
{
    int i = blockIdx.x * blockDim.x + threadIdx.x;
    if (i < E) atomicAdd(&counts[rows[i]], 1);
}

// 3-kernel parallel scan
__global__ __launch_bounds__(256) void block_scan(
    const int* __restrict__ counts, int* __restrict__ tmp, int* __restrict__ bsum, int n)
{
    __shared__ int ws[4];
    int tid = threadIdx.x, b = blockIdx.x;
    int i = b * 256 + tid;
    int lane = tid & 63, w = tid >> 6;
    int v = (i < n) ? counts[i] : 0;
    int x = v;
    #pragma unroll
    for (int off = 1; off < 64; off <<= 1) {
        int y = __shfl_up(x, off, 64);
        if (lane >= off) x += y;
    }
    if (lane == 63) ws[w] = x;
    __syncthreads();
    int add = 0;
    #pragma unroll
    for (int k = 0; k < 4; ++k) if (k < w) add += ws[k];
    x += add;
    if (i < n) tmp[i] = x;
    if (tid == 255) bsum[b] = x;
}

__global__ __launch_bounds__(256) void scan_bsums(int* __restrict__ bsum, int nb)
{
    __shared__ int ws[4];
    __shared__ int carry;
    int tid = threadIdx.x, lane = tid & 63, w = tid >> 6;
    if (tid == 0) carry = 0;
    __syncthreads();
    for (int base = 0; base < nb; base += 256) {
        int i = base + tid;
        int v = (i < nb) ? bsum[i] : 0;
        int x = v;
        #pragma unroll
        for (int off = 1; off < 64; off <<= 1) {
            int y = __shfl_up(x, off, 64);
            if (lane >= off) x += y;
        }
        if (lane == 63) ws[w] = x;
        __syncthreads();
        int add = 0;
        #pragma unroll
        for (int k = 0; k < 4; ++k) if (k < w) add += ws[k];
        int incl = x + add;
        int c = carry;
        if (i < nb) bsum[i] = incl - v + c;   // exclusive prefix
        __syncthreads();
        if (tid == 255) carry = c + incl;
        __syncthreads();
    }
}

__global__ void finalize_scan(const int* __restrict__ tmp, const int* __restrict__ boff,
                              int* __restrict__ row_ptr, int n)
{
    int i = blockIdx.x * 256 + threadIdx.x;
    if (i < n) row_ptr[i + 1] = tmp[i] + boff[i >> 8];
    if (i == 0) row_ptr[0] = 0;
}

__global__ void scatter_kernel(
    const int* __restrict__ erow, const int* __restrict__ ecol,
    const float* __restrict__ eval, const int* __restrict__ row_ptr,
    int* __restrict__ fill, int2* __restrict__ ep, int E)
{
    int i = blockIdx.x * blockDim.x + threadIdx.x;
    if (i < E) {
        int r = erow[i];
        int p = row_ptr[r] + atomicAdd(&fill[r], 1);
        ep[p] = make_int2(ecol[i], __float_as_int(eval[i]));
    }
}

// ---------------- SpMM: split-wave, 16B gathers, packed edges, bias+PReLU ----------
static __device__ __forceinline__ void fma8(float* acc, uint4 g, float v)
{
    acc[0] += v * __uint_as_float(g.x << 16);
    acc[1] += v * __uint_as_float(g.x & 0xffff0000u);
    acc[2] += v * __uint_as_float(g.y << 16);
    acc[3] += v * __uint_as_float(g.y & 0xffff0000u);
    acc[4] += v * __uint_as_float(g.z << 16);
    acc[5] += v * __uint_as_float(g.z & 0xffff0000u);
    acc[6] += v * __uint_as_float(g.w << 16);
    acc[7] += v * __uint_as_float(g.w & 0xffff0000u);
}

template<bool OUT_BF16>
__global__ __launch_bounds__(256) void spmm_split(
    const int* __restrict__ row_ptr, const int2* __restrict__ ep,
    const short* __restrict__ dense,
    const float* __restrict__ bias, const float* __restrict__ alpha_p,
    void* __restrict__ outp, int nrows)
{
    int wid  = (blockIdx.x * blockDim.x + threadIdx.x) >> 6;
    int lane = threadIdx.x & 63;
    if (wid >= nrows) return;
    int half = lane >> 5;
    int l32  = lane & 31;
    int s = row_ptr[wid], e = row_ptr[wid + 1];
    int fo = l32 * 8;                       // bf16 elem offset; 16 B per lane

    float acc[8] = {};
    int i = s;
    for (; i + 3 < e; i += 4) {             // 4 edges per iter, 2 per half
        int2 e0 = ep[i + half];
        int2 e1 = ep[i + 2 + half];
        uint4 g0 = *(const uint4*)(dense + (size_t)e0.x * NHID + fo);
        uint4 g1 = *(const uint4*)(dense + (size_t)e1.x * NHID + fo);
        fma8(acc, g0, __int_as_float(e0.y));
        fma8(acc, g1, __int_as_float(e1.y));
    }
    for (; i < e; i += 2) {                 // remainder (0..3 edges)
        int j = i + half;
        if (j < e) {
            int2 e0 = ep[j];
            uint4 g0 = *(const uint4*)(dense + (size_t)e0.x * NHID + fo);
            fma8(acc, g0, __int_as_float(e0.y));
        }
    }

    #pragma unroll
    for (int k = 0; k < 8; ++k) acc[k] += __shfl_xor(acc[k], 32, 64);

    float alpha = alpha_p[0];
    float4 b0 = *(const float4*)(bias + fo);
    float4 b1 = *(const float4*)(bias + fo + 4);
    float r[8];
    r[0] = acc[0] + b0.x; r[1] = acc[1] + b0.y; r[2] = acc[2] + b0.z; r[3] = acc[3] + b0.w;
    r[4] = acc[4] + b1.x; r[5] = acc[5] + b1.y; r[6] = acc[6] + b1.z; r[7] = acc[7] + b1.w;
    #pragma unroll
    for (int k = 0; k < 8; ++k) r[k] = (r[k] >= 0.f) ? r[k] : alpha * r[k];

    if (OUT_BF16) {
        if (half == 0) {
            uint4 o;
            o.x = pk2(r[0], r[1]); o.y = pk2(r[2], r[3]);
            o.z = pk2(r[4], r[5]); o.w = pk2(r[6], r[7]);
            *(uint4*)((short*)outp + (size_t)wid * NHID + fo) = o;
        }
    } else {
        float4 ov = half ? make_float4(r[4], r[5], r[6], r[7])
                         : make_float4(r[0], r[1], r[2], r[3]);
        *(float4*)((float*)outp + (size_t)wid * NHID + fo + half * 4) = ov;
    }
}

extern "C" void kernel_launch(void* const* d_in, const int* in_sizes, int n_in,
                              void* d_out, int out_size, void* d_ws, size_t ws_size,
                              hipStream_t stream)
{
    const float* x     = (const float*)d_in[0];
    const int*   erow  = (const int*)d_in[1];
    const int*   ecol  = (const int*)d_in[2];
    const float* eval  = (const float*)d_in[3];
    const float* W1    = (const float*)d_in[4];
    const float* b1    = (const float*)d_in[5];
    const float* W2    = (const float*)d_in[6];
    const float* b2    = (const float*)d_in[7];
    const float* alpha = (const float*)d_in[8];

    int NFEAT = 512;
    int N = in_sizes[0] / NFEAT;   // 100000
    int E = in_sizes[1];           // 3200000
    float* out = (float*)d_out;

    // Workspace layout (~128.8 MB)
    char* wsp = (char*)d_ws;
    short* support_b = (short*)wsp;  wsp += (size_t)N * NHID * sizeof(short);  // 51.2 MB
    short* h1b       = (short*)wsp;  wsp += (size_t)N * NHID * sizeof(short);  // 51.2 MB
    int2*  ep        = (int2*)wsp;   wsp += (size_t)E * sizeof(int2);          // 25.6 MB
    int*   row_ptr   = (int*)wsp;    wsp += ((size_t)(N + 1) * sizeof(int) + 15) & ~(size_t)15;
    short* W1t       = (short*)wsp;  wsp += (size_t)NFEAT * NHID * sizeof(short);
    short* W2t       = (short*)wsp;  wsp += (size_t)NHID * NHID * sizeof(short);

    // scratch aliased into h1b (dead until spmm1 writes it)
    int* fill = (int*)h1b;
    int* tmp  = fill + N;
    int* bsum = tmp + N;
    int  nblk = (N + 255) / 256;

    // ---- Weight transpose+cast ----
    transpose_cast<<<(NFEAT * NHID + 255) / 256, 256, 0, stream>>>(W1, W1t, NFEAT);
    transpose_cast<<<(NHID * NHID + 255) / 256, 256, 0, stream>>>(W2, W2t, NHID);

    // ---- CSR build ----
    hipMemsetAsync(fill, 0, (size_t)N * sizeof(int), stream);
    hist_kernel<<<(E + 255) / 256, 256, 0, stream>>>(erow, fill, E);
    block_scan<<<nblk, 256, 0, stream>>>(fill, tmp, bsum, N);
    scan_bsums<<<1, 256, 0, stream>>>(bsum, nblk);
    finalize_scan<<<nblk, 256, 0, stream>>>(tmp, bsum, row_ptr, N);
    hipMemsetAsync(fill, 0, (size_t)N * sizeof(int), stream);
    scatter_kernel<<<(E + 255) / 256, 256, 0, stream>>>(erow, ecol, eval, row_ptr, fill, ep, E);

    dim3 ggrid(2, (N + 127) / 128);
    int  spmm_blocks = (N + 3) / 4;

    // ---- Layer 1 ----
    gemm_mfma<false><<<ggrid, 256, 0, stream>>>(x, W1t, support_b, N, NFEAT);
    spmm_split<true><<<spmm_blocks, 256, 0, stream>>>(row_ptr, ep, support_b, b1, alpha, h1b, N);
    // ---- Layer 2 ----
    gemm_mfma<true><<<ggrid, 256, 0, stream>>>(h1b, W2t, support_b, N, NHID);
    spmm_split<false><<<spmm_blocks, 256, 0, stream>>>(row_ptr, ep, support_b, b2, alpha, out, N);
}